// Round 13
// baseline (271.517 us; speedup 1.0000x reference)
//
#include <hip/hip_runtime.h>
#include <stdint.h>

#define DIM   1024
#define NB    8
#define NSEQ  1024
#define NP    77
#define NH    16
#define NKVR  1104     // padded key space: text 0..76, hole 77..79, x 80..1103
#define KVP   1104     // Vt row length (kv), multiple of 8
#define QSCALE 0.18033688011112042f   // 0.125 * log2(e): folded into Wq at cast

typedef short          bf16x8 __attribute__((ext_vector_type(8)));
typedef float          f32x4  __attribute__((ext_vector_type(4)));
typedef float          f32x16 __attribute__((ext_vector_type(16)));
typedef unsigned short u16x8  __attribute__((ext_vector_type(8)));
typedef unsigned short u16x4  __attribute__((ext_vector_type(4)));
typedef unsigned int   u32x4  __attribute__((ext_vector_type(4)));

__device__ __forceinline__ float bf2f(unsigned short h) {
  return __uint_as_float(((unsigned int)h) << 16);
}
__device__ __forceinline__ unsigned short f2bf(float f) {
  unsigned int u = __float_as_uint(f);
  unsigned int r = u + 0x7FFFu + ((u >> 16) & 1u);   // RNE
  return (unsigned short)(r >> 16);
}
// pack two f32 -> 2x bf16 (RNE), lo -> bits[15:0]
__device__ __forceinline__ unsigned int cvt_pk_bf16(float lo, float hi) {
  unsigned int r;
  asm volatile("v_cvt_pk_bf16_f32 %0, %1, %2" : "=v"(r) : "v"(lo), "v"(hi));
  return r;
}

// ---------------------------------------------------------------- casts
__global__ __launch_bounds__(256) void cast_kernel(const float* __restrict__ in,
                                                   unsigned short* __restrict__ out,
                                                   int n4, float scale) {
  int i = blockIdx.x * 256 + threadIdx.x;
  if (i >= n4) return;
  float4 v = reinterpret_cast<const float4*>(in)[i];
  u16x4 o;
  o[0] = f2bf(v.x * scale); o[1] = f2bf(v.y * scale);
  o[2] = f2bf(v.z * scale); o[3] = f2bf(v.w * scale);
  reinterpret_cast<u16x4*>(out)[i] = o;
}

// x [8,1024,1024] f32 -> xkv rows batch*1104 + 80 + r
__global__ __launch_bounds__(256) void cast_x_kernel(const float* __restrict__ in,
                                                     unsigned short* __restrict__ xkv) {
  int i = blockIdx.x * 256 + threadIdx.x;
  if (i >= (NB * NSEQ * DIM) / 4) return;
  const int e    = i * 4;
  const int row  = e >> 10;
  const int cin  = e & 1023;
  const int batch = row >> 10;
  const int r     = row & 1023;
  float4 v = *reinterpret_cast<const float4*>(in + (size_t)e);
  u16x4 o;
  o[0] = f2bf(v.x); o[1] = f2bf(v.y); o[2] = f2bf(v.z); o[3] = f2bf(v.w);
  *reinterpret_cast<u16x4*>(xkv + (size_t)(batch * NKVR + 80 + r) * DIM + cin) = o;
}

// x_text [8,77,1024] f32 -> xkv rows batch*1104 + r
__global__ __launch_bounds__(256) void cast_xt_kernel(const float* __restrict__ in,
                                                      unsigned short* __restrict__ xkv) {
  int i = blockIdx.x * 256 + threadIdx.x;
  if (i >= (NB * NP * DIM) / 4) return;
  const int e    = i * 4;
  const int row  = e >> 10;
  const int cin  = e & 1023;
  const int batch = row / NP;
  const int r     = row - batch * NP;
  float4 v = *reinterpret_cast<const float4*>(in + (size_t)e);
  u16x4 o;
  o[0] = f2bf(v.x); o[1] = f2bf(v.y); o[2] = f2bf(v.z); o[3] = f2bf(v.w);
  *reinterpret_cast<u16x4*>(xkv + (size_t)(batch * NKVR + r) * DIM + cin) = o;
}

// zero xkv hole rows (77..79 per batch)
__global__ __launch_bounds__(256) void zero_hole_kernel(unsigned short* __restrict__ xkv) {
  int i = blockIdx.x * 256 + threadIdx.x;
  if (i >= (NB * 3 * DIM) / 4) return;
  const int e    = i * 4;
  const int row  = e >> 10;
  const int cin  = e & 1023;
  const int batch = row / 3;
  const int hr    = row - batch * 3;
  u16x4 z = {0, 0, 0, 0};
  *reinterpret_cast<u16x4*>(xkv + (size_t)(batch * NKVR + 77 + hr) * DIM + cin) = z;
}

// ------------------------------------------------------- async global->LDS
__device__ __forceinline__ void gload_lds16(const void* g, void* l) {
  __builtin_amdgcn_global_load_lds(
      (const __attribute__((address_space(1))) void*)g,
      (__attribute__((address_space(3))) void*)l, 16, 0, 0);
}

// ---------------------------------------------------------------- fused QKV GEMM
// A = xkv [8832][1024], B = Wqkv [3072][1024] (rows: Wq*QSCALE, Wk, Wv).
// grid: 1656 blocks (69 x 24), XCD-swizzled.
__global__ __launch_bounds__(256) void gemm_qkv(
    const unsigned short* __restrict__ A, const unsigned short* __restrict__ B,
    unsigned short* __restrict__ Qo, unsigned short* __restrict__ Ko,
    unsigned short* __restrict__ Vto) {
  __shared__ __align__(16) unsigned short As[128 * 32];
  __shared__ __align__(16) unsigned short Bs[128 * 32];
  const int id   = blockIdx.x;
  const int sid  = (id & 7) * 207 + (id >> 3);     // XCD swizzle (bijective)
  const int bx   = sid / 24;
  const int by   = sid - bx * 24;
  const int m0   = bx * 128;
  const int n0   = by * 128;
  const int t    = threadIdx.x;
  const int w    = t >> 6;
  const int lane = t & 63;
  const int wr   = w >> 1, wc = w & 1;
  const int lr   = lane & 15;
  const int k0   = (lane >> 4) * 8;

  f32x4 acc[4][4];
#pragma unroll
  for (int i = 0; i < 4; ++i)
#pragma unroll
    for (int j = 0; j < 4; ++j) acc[i][j] = f32x4{0.f, 0.f, 0.f, 0.f};

  for (int kt = 0; kt < 32; ++kt) {
#pragma unroll
    for (int p = 0; p < 2; ++p) {
      const int c   = p * 256 + t;
      const int row = c >> 2;
      const int cid = c & 3;
      gload_lds16(A + (size_t)(m0 + row) * DIM + kt * 32 + cid * 8,
                  (char*)As + p * 4096 + w * 1024);
      gload_lds16(B + (size_t)(n0 + row) * DIM + kt * 32 + cid * 8,
                  (char*)Bs + p * 4096 + w * 1024);
    }
    __syncthreads();
    bf16x8 af[4], bfr[4];
#pragma unroll
    for (int mi = 0; mi < 4; ++mi)
      af[mi] = *reinterpret_cast<const bf16x8*>(As + (wr * 64 + mi * 16 + lr) * 32 + k0);
#pragma unroll
    for (int ni = 0; ni < 4; ++ni)
      bfr[ni] = *reinterpret_cast<const bf16x8*>(Bs + (wc * 64 + ni * 16 + lr) * 32 + k0);
#pragma unroll
    for (int mi = 0; mi < 4; ++mi)
#pragma unroll
      for (int ni = 0; ni < 4; ++ni)
        acc[mi][ni] = __builtin_amdgcn_mfma_f32_16x16x32_bf16(af[mi], bfr[ni], acc[mi][ni], 0, 0, 0);
    __syncthreads();
  }

  const int rq  = lane >> 4;
  const int seg = n0 >> 10;          // 0=Q, 1=K, 2=V
  if (seg == 0) {
#pragma unroll
    for (int mi = 0; mi < 4; ++mi) {
#pragma unroll
      for (int i = 0; i < 4; ++i) {
        const int m     = m0 + wr * 64 + mi * 16 + rq * 4 + i;
        const int batch = m / NKVR;
        const int kv    = m - batch * NKVR;
        if (kv < 80) continue;                       // text/hole rows: no Q
        const size_t qrow = (size_t)batch * NSEQ + (kv - 80);
#pragma unroll
        for (int ni = 0; ni < 4; ++ni) {
          const int col = n0 + wc * 64 + ni * 16 + lr;
          Qo[qrow * DIM + col] = f2bf(acc[mi][ni][i]);
        }
      }
    }
  } else if (seg == 1) {
#pragma unroll
    for (int mi = 0; mi < 4; ++mi) {
#pragma unroll
      for (int i = 0; i < 4; ++i) {
        const int m = m0 + wr * 64 + mi * 16 + rq * 4 + i;
#pragma unroll
        for (int ni = 0; ni < 4; ++ni) {
          const int col = n0 + wc * 64 + ni * 16 + lr - 1024;
          Ko[(size_t)m * DIM + col] = f2bf(acc[mi][ni][i]);
        }
      }
    }
  } else {
#pragma unroll
    for (int mi = 0; mi < 4; ++mi) {
      const int mb    = m0 + wr * 64 + mi * 16 + rq * 4;
      const int batch = mb / NKVR;
      const int kv    = mb - batch * NKVR;           // 4-aligned, no batch crossing
#pragma unroll
      for (int ni = 0; ni < 4; ++ni) {
        const int col = n0 + wc * 64 + ni * 16 + lr - 2048;
        const int hh = col >> 6, dd = col & 63;
        u16x4 o;
        o[0] = f2bf(acc[mi][ni][0]); o[1] = f2bf(acc[mi][ni][1]);
        o[2] = f2bf(acc[mi][ni][2]); o[3] = f2bf(acc[mi][ni][3]);
        *reinterpret_cast<u16x4*>(Vto +
            ((size_t)((batch * NH + hh) * 64 + dd)) * KVP + kv) = o;
      }
    }
  }
}

// ---------------------------------------------------------------- out GEMM
__global__ __launch_bounds__(256) void gemm_out(
    const unsigned short* __restrict__ A, const unsigned short* __restrict__ B,
    float* __restrict__ C, const float* __restrict__ bias) {
  __shared__ __align__(16) unsigned short As[128 * 32];
  __shared__ __align__(16) unsigned short Bs[128 * 32];
  const int t    = threadIdx.x;
  const int w    = t >> 6;
  const int lane = t & 63;
  const int m0   = blockIdx.x * 128;
  const int n0   = blockIdx.y * 128;
  const int wr   = w >> 1, wc = w & 1;
  const int lr   = lane & 15;
  const int k0   = (lane >> 4) * 8;

  f32x4 acc[4][4];
#pragma unroll
  for (int i = 0; i < 4; ++i)
#pragma unroll
    for (int j = 0; j < 4; ++j) acc[i][j] = f32x4{0.f, 0.f, 0.f, 0.f};

  for (int kt = 0; kt < 32; ++kt) {
#pragma unroll
    for (int p = 0; p < 2; ++p) {
      const int c   = p * 256 + t;
      const int row = c >> 2;
      const int cid = c & 3;
      gload_lds16(A + (size_t)(m0 + row) * DIM + kt * 32 + cid * 8,
                  (char*)As + p * 4096 + w * 1024);
      gload_lds16(B + (size_t)(n0 + row) * DIM + kt * 32 + cid * 8,
                  (char*)Bs + p * 4096 + w * 1024);
    }
    __syncthreads();
    bf16x8 af[4], bfr[4];
#pragma unroll
    for (int mi = 0; mi < 4; ++mi)
      af[mi] = *reinterpret_cast<const bf16x8*>(As + (wr * 64 + mi * 16 + lr) * 32 + k0);
#pragma unroll
    for (int ni = 0; ni < 4; ++ni)
      bfr[ni] = *reinterpret_cast<const bf16x8*>(Bs + (wc * 64 + ni * 16 + lr) * 32 + k0);
#pragma unroll
    for (int mi = 0; mi < 4; ++mi)
#pragma unroll
      for (int ni = 0; ni < 4; ++ni)
        acc[mi][ni] = __builtin_amdgcn_mfma_f32_16x16x32_bf16(af[mi], bfr[ni], acc[mi][ni], 0, 0, 0);
    __syncthreads();
  }

  const int rq = lane >> 4;
#pragma unroll
  for (int mi = 0; mi < 4; ++mi) {
#pragma unroll
    for (int i = 0; i < 4; ++i) {
      const int m = m0 + wr * 64 + mi * 16 + rq * 4 + i;
#pragma unroll
      for (int ni = 0; ni < 4; ++ni) {
        const int col = n0 + wc * 64 + ni * 16 + lr;
        C[(size_t)m * DIM + col] = acc[mi][ni][i] + bias[col];
      }
    }
  }
}

// ---------------------------------------------------------------- MFMA attention
// Swapped-QK 32x32 (no main-loop LDS) + cross-block K register double-buffer
// (akA/akB, statically named) + coalesced O epilogue via per-wave LDS stage.
// grid (128 bh, 16 qtile), block 128 (2 waves x 32 q-rows).
__global__ __launch_bounds__(128, 4) void attn_mfma(
    const unsigned short* __restrict__ Q, const unsigned short* __restrict__ K,
    const unsigned short* __restrict__ Vt, const float* __restrict__ gate,
    unsigned short* __restrict__ O) {
  const int wid  = threadIdx.x >> 6;
  const int lane = threadIdx.x & 63;
  const int ql   = lane & 31;
  const int hi   = lane >> 5;
  const int bh   = blockIdx.x;
  const int b    = bh >> 4;
  const int h    = bh & 15;
  const int q0   = blockIdx.y * 64 + wid * 32;

  __shared__ float v0f[2][64];
  __shared__ __align__(16) unsigned short o_lds[2][32 * 72];   // stride 72 shorts = 144B

  const unsigned short* Vtbase = Vt + ((size_t)((b * NH + h) * 64)) * KVP;
  const unsigned short* Kbase  = K  + ((size_t)b * NKVR) * DIM + h * 64 + hi * 8;

  // key-0 V column, staged per-wave (lane = d)
  v0f[wid][lane] = bf2f(Vtbase[(size_t)lane * KVP]);

  // Q as B-frag: B[k=hi*8+e][col=ql]
  bf16x8 bq[4];
  const unsigned short* Qrow = Q + ((size_t)(b * NSEQ + q0 + ql)) * DIM + h * 64 + hi * 8;
#pragma unroll
  for (int j = 0; j < 4; ++j)
    bq[j] = *reinterpret_cast<const bf16x8*>(Qrow + j * 16);

  f32x16 o0, o1;
#pragma unroll
  for (int r = 0; r < 16; ++r) { o0[r] = 0.f; o1[r] = 0.f; }
  float lsum = 0.f;

  auto load_k = [&](int kbase, bf16x8 (&ak)[4]) {
    int krow = kbase + ql;
    krow = krow < NKVR ? krow : (NKVR - 1);
    const unsigned short* kr = Kbase + (size_t)krow * DIM;
#pragma unroll
    for (int j = 0; j < 4; ++j)
      ak[j] = *reinterpret_cast<const bf16x8*>(kr + j * 16);
  };

  // mm: 0=none, 1=key0, 2=holes(77..79), 3=tail(>=1104; second k-step skipped)
  auto body = [&](int kbase, int mm, bf16x8 (&ak)[4],
                  bool pf, int nkbase, bf16x8 (&nak)[4]) {
    // S^T = K Q  (col = q = ql, row-reg r -> key kbase + (r&3)+8*(r>>2)+4*hi)
    f32x16 s;
#pragma unroll
    for (int r = 0; r < 16; ++r) s[r] = 0.f;
#pragma unroll
    for (int j = 0; j < 4; ++j)
      s = __builtin_amdgcn_mfma_f32_32x32x16_bf16(ak[j], bq[j], s, 0, 0, 0);

    // V A-frags for current block (fly under exp/pack)
    bf16x8 av0[2], av1[2];
#pragma unroll
    for (int n = 0; n < 2; ++n)
      av0[n] = *reinterpret_cast<const bf16x8*>(
          Vtbase + (size_t)(n * 32 + ql) * KVP + kbase + hi * 8);
    if (mm != 3) {
#pragma unroll
      for (int n = 0; n < 2; ++n)
        av1[n] = *reinterpret_cast<const bf16x8*>(
            Vtbase + (size_t)(n * 32 + ql) * KVP + kbase + 16 + hi * 8);
    }
    // prefetch next block's K (consumed at next body's QK, ~1 block of cover)
    if (pf) load_k(nkbase, nak);

    // static masks
    if (mm == 1) {
      if (hi == 0) s[0] = -1.0e30f;
    } else if (mm == 2) {
      if (hi == 1) { s[5] = -1.0e30f; s[6] = -1.0e30f; s[7] = -1.0e30f; }
    } else if (mm == 3) {
#pragma unroll
      for (int r = 8; r < 16; ++r) s[r] = -1.0e30f;
    }

    // exp2 (scale pre-folded into Q) + per-lane row sum
    float ts = 0.f;
#pragma unroll
    for (int r = 0; r < 16; ++r) { s[r] = __builtin_exp2f(s[r]); ts += s[r]; }
    lsum += ts;

    // pack P^T B-frags (cvt_pk + lane<->lane+32 exchange) and accumulate PV
    {
      const unsigned int p0 = cvt_pk_bf16(s[0], s[1]);
      const unsigned int p1 = cvt_pk_bf16(s[2], s[3]);
      const unsigned int p2 = cvt_pk_bf16(s[4], s[5]);
      const unsigned int p3 = cvt_pk_bf16(s[6], s[7]);
      const unsigned int t0 = (unsigned int)__shfl_xor((int)p0, 32);
      const unsigned int t1 = (unsigned int)__shfl_xor((int)p1, 32);
      const unsigned int t2 = (unsigned int)__shfl_xor((int)p2, 32);
      const unsigned int t3 = (unsigned int)__shfl_xor((int)p3, 32);
      u32x4 wv;
      wv[0] = hi ? t2 : p0;
      wv[1] = hi ? t3 : p1;
      wv[2] = hi ? p2 : t0;
      wv[3] = hi ? p3 : t1;
      const bf16x8 bp = __builtin_bit_cast(bf16x8, wv);
      o0 = __builtin_amdgcn_mfma_f32_32x32x16_bf16(av0[0], bp, o0, 0, 0, 0);
      o1 = __builtin_amdgcn_mfma_f32_32x32x16_bf16(av0[1], bp, o1, 0, 0, 0);
    }
    if (mm != 3) {
      const unsigned int p0 = cvt_pk_bf16(s[8],  s[9]);
      const unsigned int p1 = cvt_pk_bf16(s[10], s[11]);
      const unsigned int p2 = cvt_pk_bf16(s[12], s[13]);
      const unsigned int p3 = cvt_pk_bf16(s[14], s[15]);
      const unsigned int t0 = (unsigned int)__shfl_xor((int)p0, 32);
      const unsigned int t1 = (unsigned int)__shfl_xor((int)p1, 32);
      const unsigned int t2 = (unsigned int)__shfl_xor((int)p2, 32);
      const unsigned int t3 = (unsigned int)__shfl_xor((int)p3, 32);
      u32x4 wv;
      wv[0] = hi ? t2 : p0;
      wv[1] = hi ? t3 : p1;
      wv[2] = hi ? p2 : t0;
      wv[3] = hi ? p3 : t1;
      const bf16x8 bp = __builtin_bit_cast(bf16x8, wv);
      o0 = __builtin_amdgcn_mfma_f32_32x32x16_bf16(av1[0], bp, o0, 0, 0, 0);
      o1 = __builtin_amdgcn_mfma_f32_32x32x16_bf16(av1[1], bp, o1, 0, 0, 0);
    }
  };

  bf16x8 akA[4], akB[4];
  load_k(0, akA);
  body(0,  1, akA, true, 32,  akB);
  body(32, 0, akB, true, 64,  akA);
  body(64, 2, akA, true, 96,  akB);
  body(96, 0, akB, true, 128, akA);
  for (int i = 4; i < 34; i += 2) {
    body(32 * i,       0, akA, true, 32 * (i + 1), akB);
    body(32 * (i + 1), 0, akB, true, 32 * (i + 2), akA);
  }
  body(1088, 3, akA, false, 0, akB);

  // ---- epilogue: row-sum combine, scale, gated key-0, LDS-stage, coalesced store
  const float lt  = lsum + __shfl_xor(lsum, 32);
  const float inv = 1.f / lt;
  const float gv  = tanhf(gate[h]);
#pragma unroll
  for (int n = 0; n < 2; ++n) {
#pragma unroll
    for (int g = 0; g < 4; ++g) {
      const int col = n * 32 + 8 * g + 4 * hi;
      const float4 vv = *reinterpret_cast<const float4*>(&v0f[wid][col]);
      float e0, e1, e2, e3;
      if (n == 0) {
        e0 = o0[4 * g + 0]; e1 = o0[4 * g + 1]; e2 = o0[4 * g + 2]; e3 = o0[4 * g + 3];
      } else {
        e0 = o1[4 * g + 0]; e1 = o1[4 * g + 1]; e2 = o1[4 * g + 2]; e3 = o1[4 * g + 3];
      }
      u16x4 ov;
      ov[0] = f2bf(e0 * inv + gv * vv.x);
      ov[1] = f2bf(e1 * inv + gv * vv.y);
      ov[2] = f2bf(e2 * inv + gv * vv.z);
      ov[3] = f2bf(e3 * inv + gv * vv.w);
      *reinterpret_cast<u16x4*>(&o_lds[wid][ql * 72 + col]) = ov;
    }
  }
  __syncthreads();
  unsigned short* Obase = O + ((size_t)(b * NSEQ + q0)) * DIM + h * 64;
  const int rr = lane >> 3;   // 0..7
  const int cc = lane & 7;    // 0..7
#pragma unroll
  for (int it = 0; it < 4; ++it) {
    const int row = it * 8 + rr;
    const u16x8 v8 = *reinterpret_cast<const u16x8*>(&o_lds[wid][row * 72 + cc * 8]);
    *reinterpret_cast<u16x8*>(Obase + (size_t)row * DIM + cc * 8) = v8;
  }
}

// ---------------------------------------------------------------- LayerNorm
__global__ __launch_bounds__(256) void ln_kernel(const unsigned short* __restrict__ in,
                                                 const float* __restrict__ g,
                                                 const float* __restrict__ beta,
                                                 unsigned short* __restrict__ out) {
  const int row = blockIdx.x;
  const int t   = threadIdx.x;
  const u16x4 hv = *reinterpret_cast<const u16x4*>(in + (size_t)row * DIM + t * 4);
  const float v0 = bf2f(hv[0]), v1 = bf2f(hv[1]), v2 = bf2f(hv[2]), v3 = bf2f(hv[3]);
  float sum = v0 + v1 + v2 + v3;
  float sq  = v0 * v0 + v1 * v1 + v2 * v2 + v3 * v3;
  for (int off = 32; off; off >>= 1) {
    sum += __shfl_xor(sum, off);
    sq  += __shfl_xor(sq, off);
  }
  __shared__ float red[8];
  if ((t & 63) == 0) { red[t >> 6] = sum; red[4 + (t >> 6)] = sq; }
  __syncthreads();
  sum = red[0] + red[1] + red[2] + red[3];
  sq  = red[4] + red[5] + red[6] + red[7];
  const float mu  = sum * (1.f / DIM);
  const float var = sq * (1.f / DIM) - mu * mu;
  const float rs  = 1.f / sqrtf(var + 1e-5f);
  const float4 gv = *reinterpret_cast<const float4*>(g + t * 4);
  const float4 bv = *reinterpret_cast<const float4*>(beta + t * 4);
  u16x4 o;
  o[0] = f2bf((v0 - mu) * rs * gv.x + bv.x);
  o[1] = f2bf((v1 - mu) * rs * gv.y + bv.y);
  o[2] = f2bf((v2 - mu) * rs * gv.z + bv.z);
  o[3] = f2bf((v3 - mu) * rs * gv.w + bv.w);
  *reinterpret_cast<u16x4*>(out + (size_t)row * DIM + t * 4) = o;
}

// ---------------------------------------------------------------- launch
extern "C" void kernel_launch(void* const* d_in, const int* in_sizes, int n_in,
                              void* d_out, int out_size, void* d_ws, size_t ws_size,
                              hipStream_t stream) {
  const float* x    = (const float*)d_in[0];
  const float* xt   = (const float*)d_in[1];
  const float* Wq   = (const float*)d_in[2];
  const float* Wk   = (const float*)d_in[3];
  const float* Wv   = (const float*)d_in[4];
  const float* gate = (const float*)d_in[5];
  const float* lng  = (const float*)d_in[6];
  const float* lnbt = (const float*)d_in[7];
  const float* Wp   = (const float*)d_in[8];
  const float* bp   = (const float*)d_in[9];

  char* ws = (char*)d_ws;
  unsigned short* xkvb = (unsigned short*)(ws + 0);          // 18,087,936
  unsigned short* Wqkv = (unsigned short*)(ws + 18087936);   //  6,291,456
  unsigned short* Qb   = (unsigned short*)(ws + 24379392);   // 16,777,216
  unsigned short* Kb   = (unsigned short*)(ws + 41156608);   // 18,087,936
  unsigned short* Vtb  = (unsigned short*)(ws + 59244544);   // 18,087,936 (end 77,332,480)
  unsigned short* attnb = xkvb;   // xkv dead after QKV GEMM
  unsigned short* lnob  = Qb;     // Q dead after attention
  unsigned short* Wpb   = Wqkv;   // Wqkv dead after QKV GEMM

  cast_x_kernel<<<dim3((NB * NSEQ * DIM / 4 + 255) / 256), 256, 0, stream>>>(x, xkvb);
  cast_xt_kernel<<<dim3((NB * NP * DIM / 4 + 255) / 256), 256, 0, stream>>>(xt, xkvb);
  zero_hole_kernel<<<dim3((NB * 3 * DIM / 4 + 255) / 256), 256, 0, stream>>>(xkvb);
  const int w4 = DIM * DIM / 4;
  cast_kernel<<<dim3((w4 + 255) / 256), 256, 0, stream>>>(Wq, Wqkv, w4, QSCALE);
  cast_kernel<<<dim3((w4 + 255) / 256), 256, 0, stream>>>(Wk, Wqkv + DIM * DIM, w4, 1.0f);
  cast_kernel<<<dim3((w4 + 255) / 256), 256, 0, stream>>>(Wv, Wqkv + 2 * DIM * DIM, w4, 1.0f);

  gemm_qkv<<<dim3(69 * 24), 256, 0, stream>>>(xkvb, Wqkv, Qb, Kb, Vtb);

  attn_mfma<<<dim3(128, 16), 128, 0, stream>>>(Qb, Kb, Vtb, gate, attnb);

  cast_kernel<<<dim3((w4 + 255) / 256), 256, 0, stream>>>(Wp, Wpb, w4, 1.0f);
  ln_kernel<<<dim3(NB * NSEQ), 256, 0, stream>>>(attnb, lng, lnbt, lnob);
  gemm_out<<<dim3(64, 8), 256, 0, stream>>>(lnob, Wpb, (float*)d_out, bp);
}

// Round 14
// 256.711 us; speedup vs baseline: 1.0577x; 1.0577x over previous
//
#include <hip/hip_runtime.h>
#include <stdint.h>

#define DIM   1024
#define NB    8
#define NSEQ  1024
#define NP    77
#define NH    16
#define NKVR  1104     // padded key space: text 0..76, hole 77..79, x 80..1103
#define KVP   1104     // Vt row length (kv), multiple of 8
#define NTILE 18       // ceil(1152/64) key tiles of 64
#define PLD   67       // P LDS row stride (f32): odd -> ~2-way banks on b128 reads
#define QSCALE 0.18033688011112042f   // 0.125 * log2(e): folded into Wq at cast

typedef short          bf16x8 __attribute__((ext_vector_type(8)));
typedef float          f32x4  __attribute__((ext_vector_type(4)));
typedef unsigned short u16x8  __attribute__((ext_vector_type(8)));
typedef unsigned short u16x4  __attribute__((ext_vector_type(4)));
typedef unsigned int   u32x4  __attribute__((ext_vector_type(4)));

__device__ __forceinline__ float bf2f(unsigned short h) {
  return __uint_as_float(((unsigned int)h) << 16);
}
__device__ __forceinline__ unsigned short f2bf(float f) {
  unsigned int u = __float_as_uint(f);
  unsigned int r = u + 0x7FFFu + ((u >> 16) & 1u);   // RNE
  return (unsigned short)(r >> 16);
}
// pack two f32 -> 2x bf16 (RNE), lo -> bits[15:0]
__device__ __forceinline__ unsigned int cvt_pk_bf16(float lo, float hi) {
  unsigned int r;
  asm volatile("v_cvt_pk_bf16_f32 %0, %1, %2" : "=v"(r) : "v"(lo), "v"(hi));
  return r;
}

// ---------------------------------------------------------------- casts
__global__ __launch_bounds__(256) void cast_kernel(const float* __restrict__ in,
                                                   unsigned short* __restrict__ out,
                                                   int n4, float scale) {
  int i = blockIdx.x * 256 + threadIdx.x;
  if (i >= n4) return;
  float4 v = reinterpret_cast<const float4*>(in)[i];
  u16x4 o;
  o[0] = f2bf(v.x * scale); o[1] = f2bf(v.y * scale);
  o[2] = f2bf(v.z * scale); o[3] = f2bf(v.w * scale);
  reinterpret_cast<u16x4*>(out)[i] = o;
}

// x [8,1024,1024] f32 -> xkv rows batch*1104 + 80 + r
__global__ __launch_bounds__(256) void cast_x_kernel(const float* __restrict__ in,
                                                     unsigned short* __restrict__ xkv) {
  int i = blockIdx.x * 256 + threadIdx.x;
  if (i >= (NB * NSEQ * DIM) / 4) return;
  const int e    = i * 4;
  const int row  = e >> 10;
  const int cin  = e & 1023;
  const int batch = row >> 10;
  const int r     = row & 1023;
  float4 v = *reinterpret_cast<const float4*>(in + (size_t)e);
  u16x4 o;
  o[0] = f2bf(v.x); o[1] = f2bf(v.y); o[2] = f2bf(v.z); o[3] = f2bf(v.w);
  *reinterpret_cast<u16x4*>(xkv + (size_t)(batch * NKVR + 80 + r) * DIM + cin) = o;
}

// x_text [8,77,1024] f32 -> xkv rows batch*1104 + r
__global__ __launch_bounds__(256) void cast_xt_kernel(const float* __restrict__ in,
                                                      unsigned short* __restrict__ xkv) {
  int i = blockIdx.x * 256 + threadIdx.x;
  if (i >= (NB * NP * DIM) / 4) return;
  const int e    = i * 4;
  const int row  = e >> 10;
  const int cin  = e & 1023;
  const int batch = row / NP;
  const int r     = row - batch * NP;
  float4 v = *reinterpret_cast<const float4*>(in + (size_t)e);
  u16x4 o;
  o[0] = f2bf(v.x); o[1] = f2bf(v.y); o[2] = f2bf(v.z); o[3] = f2bf(v.w);
  *reinterpret_cast<u16x4*>(xkv + (size_t)(batch * NKVR + r) * DIM + cin) = o;
}

// zero xkv hole rows (77..79 per batch)
__global__ __launch_bounds__(256) void zero_hole_kernel(unsigned short* __restrict__ xkv) {
  int i = blockIdx.x * 256 + threadIdx.x;
  if (i >= (NB * 3 * DIM) / 4) return;
  const int e    = i * 4;
  const int row  = e >> 10;
  const int cin  = e & 1023;
  const int batch = row / 3;
  const int hr    = row - batch * 3;
  u16x4 z = {0, 0, 0, 0};
  *reinterpret_cast<u16x4*>(xkv + (size_t)(batch * NKVR + 77 + hr) * DIM + cin) = z;
}

// ------------------------------------------------------- async global->LDS
__device__ __forceinline__ void gload_lds16(const void* g, void* l) {
  __builtin_amdgcn_global_load_lds(
      (const __attribute__((address_space(1))) void*)g,
      (__attribute__((address_space(3))) void*)l, 16, 0, 0);
}

// ---------------------------------------------------------------- fused QKV GEMM
// A = xkv [8832][1024], B = Wqkv [3072][1024] (rows: Wq*QSCALE, Wk, Wv).
// grid: 1656 blocks (69 x 24), XCD-swizzled.
__global__ __launch_bounds__(256) void gemm_qkv(
    const unsigned short* __restrict__ A, const unsigned short* __restrict__ B,
    unsigned short* __restrict__ Qo, unsigned short* __restrict__ Ko,
    unsigned short* __restrict__ Vto) {
  __shared__ __align__(16) unsigned short As[128 * 32];
  __shared__ __align__(16) unsigned short Bs[128 * 32];
  const int id   = blockIdx.x;
  const int sid  = (id & 7) * 207 + (id >> 3);     // XCD swizzle (bijective)
  const int bx   = sid / 24;
  const int by   = sid - bx * 24;
  const int m0   = bx * 128;
  const int n0   = by * 128;
  const int t    = threadIdx.x;
  const int w    = t >> 6;
  const int lane = t & 63;
  const int wr   = w >> 1, wc = w & 1;
  const int lr   = lane & 15;
  const int k0   = (lane >> 4) * 8;

  f32x4 acc[4][4];
#pragma unroll
  for (int i = 0; i < 4; ++i)
#pragma unroll
    for (int j = 0; j < 4; ++j) acc[i][j] = f32x4{0.f, 0.f, 0.f, 0.f};

  for (int kt = 0; kt < 32; ++kt) {
#pragma unroll
    for (int p = 0; p < 2; ++p) {
      const int c   = p * 256 + t;
      const int row = c >> 2;
      const int cid = c & 3;
      gload_lds16(A + (size_t)(m0 + row) * DIM + kt * 32 + cid * 8,
                  (char*)As + p * 4096 + w * 1024);
      gload_lds16(B + (size_t)(n0 + row) * DIM + kt * 32 + cid * 8,
                  (char*)Bs + p * 4096 + w * 1024);
    }
    __syncthreads();
    bf16x8 af[4], bfr[4];
#pragma unroll
    for (int mi = 0; mi < 4; ++mi)
      af[mi] = *reinterpret_cast<const bf16x8*>(As + (wr * 64 + mi * 16 + lr) * 32 + k0);
#pragma unroll
    for (int ni = 0; ni < 4; ++ni)
      bfr[ni] = *reinterpret_cast<const bf16x8*>(Bs + (wc * 64 + ni * 16 + lr) * 32 + k0);
#pragma unroll
    for (int mi = 0; mi < 4; ++mi)
#pragma unroll
      for (int ni = 0; ni < 4; ++ni)
        acc[mi][ni] = __builtin_amdgcn_mfma_f32_16x16x32_bf16(af[mi], bfr[ni], acc[mi][ni], 0, 0, 0);
    __syncthreads();
  }

  const int rq  = lane >> 4;
  const int seg = n0 >> 10;          // 0=Q, 1=K, 2=V
  if (seg == 0) {
#pragma unroll
    for (int mi = 0; mi < 4; ++mi) {
#pragma unroll
      for (int i = 0; i < 4; ++i) {
        const int m     = m0 + wr * 64 + mi * 16 + rq * 4 + i;
        const int batch = m / NKVR;
        const int kv    = m - batch * NKVR;
        if (kv < 80) continue;                       // text/hole rows: no Q
        const size_t qrow = (size_t)batch * NSEQ + (kv - 80);
#pragma unroll
        for (int ni = 0; ni < 4; ++ni) {
          const int col = n0 + wc * 64 + ni * 16 + lr;
          Qo[qrow * DIM + col] = f2bf(acc[mi][ni][i]);
        }
      }
    }
  } else if (seg == 1) {
#pragma unroll
    for (int mi = 0; mi < 4; ++mi) {
#pragma unroll
      for (int i = 0; i < 4; ++i) {
        const int m = m0 + wr * 64 + mi * 16 + rq * 4 + i;
#pragma unroll
        for (int ni = 0; ni < 4; ++ni) {
          const int col = n0 + wc * 64 + ni * 16 + lr - 1024;
          Ko[(size_t)m * DIM + col] = f2bf(acc[mi][ni][i]);
        }
      }
    }
  } else {
#pragma unroll
    for (int mi = 0; mi < 4; ++mi) {
      const int mb    = m0 + wr * 64 + mi * 16 + rq * 4;
      const int batch = mb / NKVR;
      const int kv    = mb - batch * NKVR;           // 4-aligned, no batch crossing
#pragma unroll
      for (int ni = 0; ni < 4; ++ni) {
        const int col = n0 + wc * 64 + ni * 16 + lr - 2048;
        const int hh = col >> 6, dd = col & 63;
        u16x4 o;
        o[0] = f2bf(acc[mi][ni][0]); o[1] = f2bf(acc[mi][ni][1]);
        o[2] = f2bf(acc[mi][ni][2]); o[3] = f2bf(acc[mi][ni][3]);
        *reinterpret_cast<u16x4*>(Vto +
            ((size_t)((batch * NH + hh) * 64 + dd)) * KVP + kv) = o;
      }
    }
  }
}

// ---------------------------------------------------------------- out GEMM
__global__ __launch_bounds__(256) void gemm_out(
    const unsigned short* __restrict__ A, const unsigned short* __restrict__ B,
    float* __restrict__ C, const float* __restrict__ bias) {
  __shared__ __align__(16) unsigned short As[128 * 32];
  __shared__ __align__(16) unsigned short Bs[128 * 32];
  const int t    = threadIdx.x;
  const int w    = t >> 6;
  const int lane = t & 63;
  const int m0   = blockIdx.x * 128;
  const int n0   = blockIdx.y * 128;
  const int wr   = w >> 1, wc = w & 1;
  const int lr   = lane & 15;
  const int k0   = (lane >> 4) * 8;

  f32x4 acc[4][4];
#pragma unroll
  for (int i = 0; i < 4; ++i)
#pragma unroll
    for (int j = 0; j < 4; ++j) acc[i][j] = f32x4{0.f, 0.f, 0.f, 0.f};

  for (int kt = 0; kt < 32; ++kt) {
#pragma unroll
    for (int p = 0; p < 2; ++p) {
      const int c   = p * 256 + t;
      const int row = c >> 2;
      const int cid = c & 3;
      gload_lds16(A + (size_t)(m0 + row) * DIM + kt * 32 + cid * 8,
                  (char*)As + p * 4096 + w * 1024);
      gload_lds16(B + (size_t)(n0 + row) * DIM + kt * 32 + cid * 8,
                  (char*)Bs + p * 4096 + w * 1024);
    }
    __syncthreads();
    bf16x8 af[4], bfr[4];
#pragma unroll
    for (int mi = 0; mi < 4; ++mi)
      af[mi] = *reinterpret_cast<const bf16x8*>(As + (wr * 64 + mi * 16 + lr) * 32 + k0);
#pragma unroll
    for (int ni = 0; ni < 4; ++ni)
      bfr[ni] = *reinterpret_cast<const bf16x8*>(Bs + (wc * 64 + ni * 16 + lr) * 32 + k0);
#pragma unroll
    for (int mi = 0; mi < 4; ++mi)
#pragma unroll
      for (int ni = 0; ni < 4; ++ni)
        acc[mi][ni] = __builtin_amdgcn_mfma_f32_16x16x32_bf16(af[mi], bfr[ni], acc[mi][ni], 0, 0, 0);
    __syncthreads();
  }

  const int rq = lane >> 4;
#pragma unroll
  for (int mi = 0; mi < 4; ++mi) {
#pragma unroll
    for (int i = 0; i < 4; ++i) {
      const int m = m0 + wr * 64 + mi * 16 + rq * 4 + i;
#pragma unroll
      for (int ni = 0; ni < 4; ++ni) {
        const int col = n0 + wc * 64 + ni * 16 + lr;
        C[(size_t)m * DIM + col] = acc[mi][ni][i] + bias[col];
      }
    }
  }
}

// ---------------------------------------------------------------- MFMA attention
// R8 structure: grid (128 bh, 8 qtile), block 256 (4 waves x 32 q-rows).
// Single-buffered per-tile pipeline: K batch-load -> QK -> V issue-early
// -> mask/exp2/P-LDS -> PV from registers. Q pre-scaled by 0.125*log2e.
__global__ __launch_bounds__(256) void attn_mfma(
    const unsigned short* __restrict__ Q, const unsigned short* __restrict__ K,
    const unsigned short* __restrict__ Vt, const float* __restrict__ gate,
    unsigned short* __restrict__ O) {
  const int wid  = threadIdx.x >> 6;
  const int lane = threadIdx.x & 63;
  const int lr   = lane & 15;
  const int lg   = lane >> 4;
  const int bh   = blockIdx.x;
  const int b    = bh >> 4;
  const int h    = bh & 15;
  const int q0   = blockIdx.y * 128 + wid * 32;

  __shared__ __align__(16) float p_lds[4][32 * PLD];   // per-wave f32 P tile

  bf16x8 aq[2][2];
#pragma unroll
  for (int mi = 0; mi < 2; ++mi)
#pragma unroll
    for (int kf = 0; kf < 2; ++kf)
      aq[mi][kf] = *reinterpret_cast<const bf16x8*>(
          Q + ((size_t)(b * NSEQ + q0 + mi * 16 + lr)) * DIM + h * 64 + kf * 32 + lg * 8);

  f32x4 accO[2][4];
#pragma unroll
  for (int mi = 0; mi < 2; ++mi)
#pragma unroll
    for (int n = 0; n < 4; ++n) accO[mi][n] = f32x4{0.f, 0.f, 0.f, 0.f};
  float lsum[2][4];
#pragma unroll
  for (int mi = 0; mi < 2; ++mi)
#pragma unroll
    for (int r = 0; r < 4; ++r) lsum[mi][r] = 0.f;

  const unsigned short* Kbase  = K  + ((size_t)b * NKVR) * DIM + h * 64 + lg * 8;
  const unsigned short* Vtbase = Vt + ((size_t)((b * NH + h) * 64)) * KVP;
  float* pl = p_lds[wid];

  for (int tkv = 0; tkv < NTILE; ++tkv) {
    const int kv0 = tkv * 64;
    // ---- issue all K loads for this tile (batched; consumed by QK below)
    bf16x8 bk[4][2];
#pragma unroll
    for (int ni = 0; ni < 4; ++ni) {
      int kvn = kv0 + ni * 16 + lr;
      kvn = kvn < (NKVR - 1) ? kvn : (NKVR - 1);
      const unsigned short* kr = Kbase + (size_t)kvn * DIM;
#pragma unroll
      for (int kf = 0; kf < 2; ++kf)
        bk[ni][kf] = *reinterpret_cast<const bf16x8*>(kr + kf * 32);
    }
    // ---- S = Q K^T  (Q pre-scaled; S in log2 units)
    f32x4 S[2][4];
#pragma unroll
    for (int mi = 0; mi < 2; ++mi)
#pragma unroll
      for (int ni = 0; ni < 4; ++ni) S[mi][ni] = f32x4{0.f, 0.f, 0.f, 0.f};
#pragma unroll
    for (int ni = 0; ni < 4; ++ni)
#pragma unroll
      for (int kf = 0; kf < 2; ++kf)
#pragma unroll
        for (int mi = 0; mi < 2; ++mi)
          S[mi][ni] = __builtin_amdgcn_mfma_f32_16x16x32_bf16(aq[mi][kf], bk[ni][kf], S[mi][ni], 0, 0, 0);
    // ---- issue all V loads now; they fly during exp2 + P-LDS roundtrip
    bf16x8 bv[4][2];
#pragma unroll
    for (int n = 0; n < 4; ++n) {
      const unsigned short* vr = Vtbase + (size_t)(n * 16 + lr) * KVP;
#pragma unroll
      for (int kf = 0; kf < 2; ++kf) {
        int kvb = kv0 + kf * 32 + lg * 8;
        kvb = kvb < (KVP - 8) ? kvb : (KVP - 8);
        bv[n][kf] = *reinterpret_cast<const bf16x8*>(vr + kvb);
      }
    }
    // ---- mask (tiles containing key 0, the hole 77..79, or tail >=1104)
    if (tkv < 2 || tkv == NTILE - 1) {
#pragma unroll
      for (int ni = 0; ni < 4; ++ni) {
        const int gk = kv0 + ni * 16 + lr;
        const bool bad = (gk == 0) || ((unsigned)(gk - 77) < 3u) || (gk >= NKVR);
        if (bad) {
#pragma unroll
          for (int mi = 0; mi < 2; ++mi)
#pragma unroll
            for (int r = 0; r < 4; ++r) S[mi][ni][r] = -1.0e30f;
        }
      }
    }
    // ---- exp2, per-lane partial sums, P -> LDS (f32)
#pragma unroll
    for (int mi = 0; mi < 2; ++mi) {
#pragma unroll
      for (int ni = 0; ni < 4; ++ni) {
#pragma unroll
        for (int r = 0; r < 4; ++r)
          S[mi][ni][r] = __builtin_exp2f(S[mi][ni][r]);
      }
#pragma unroll
      for (int r = 0; r < 4; ++r)
        lsum[mi][r] += (S[mi][0][r] + S[mi][1][r]) + (S[mi][2][r] + S[mi][3][r]);
#pragma unroll
      for (int ni = 0; ni < 4; ++ni) {
        float* pw = pl + (size_t)(mi * 16 + lg * 4) * PLD + ni * 16 + lr;
        pw[0 * PLD] = S[mi][ni][0];
        pw[1 * PLD] = S[mi][ni][1];
        pw[2 * PLD] = S[mi][ni][2];
        pw[3 * PLD] = S[mi][ni][3];
      }
    }
    // ---- O += P V
    bf16x8 pa[2][2];
#pragma unroll
    for (int mi = 0; mi < 2; ++mi) {
#pragma unroll
      for (int kf = 0; kf < 2; ++kf) {
        const float* pr = pl + (size_t)(mi * 16 + lr) * PLD + kf * 32 + lg * 8;
        const float4 pa0 = *reinterpret_cast<const float4*>(pr);
        const float4 pa1 = *reinterpret_cast<const float4*>(pr + 4);
        u32x4 pk;
        pk[0] = cvt_pk_bf16(pa0.x, pa0.y);
        pk[1] = cvt_pk_bf16(pa0.z, pa0.w);
        pk[2] = cvt_pk_bf16(pa1.x, pa1.y);
        pk[3] = cvt_pk_bf16(pa1.z, pa1.w);
        pa[mi][kf] = __builtin_bit_cast(bf16x8, pk);
      }
    }
#pragma unroll
    for (int n = 0; n < 4; ++n)
#pragma unroll
      for (int kf = 0; kf < 2; ++kf)
#pragma unroll
        for (int mi = 0; mi < 2; ++mi)
          accO[mi][n] = __builtin_amdgcn_mfma_f32_16x16x32_bf16(pa[mi][kf], bv[n][kf], accO[mi][n], 0, 0, 0);
  }

  // ---- single cross-lane sum reduce, then epilogue
#pragma unroll
  for (int mi = 0; mi < 2; ++mi) {
#pragma unroll
    for (int r = 0; r < 4; ++r) {
      float s = lsum[mi][r];
      s += __shfl_xor(s, 1);
      s += __shfl_xor(s, 2);
      s += __shfl_xor(s, 4);
      s += __shfl_xor(s, 8);
      lsum[mi][r] = 1.f / s;
    }
  }
  const float gv = tanhf(gate[h]);
#pragma unroll
  for (int mi = 0; mi < 2; ++mi) {
#pragma unroll
    for (int n = 0; n < 4; ++n) {
      const float v0 = bf2f(Vtbase[(size_t)(n * 16 + lr) * KVP]);   // key 0
#pragma unroll
      for (int r = 0; r < 4; ++r) {
        const float o = accO[mi][n][r] * lsum[mi][r] + gv * v0;
        const int q = q0 + mi * 16 + lg * 4 + r;
        O[((size_t)(b * NSEQ + q)) * DIM + h * 64 + n * 16 + lr] = f2bf(o);
      }
    }
  }
}

// ---------------------------------------------------------------- LayerNorm
__global__ __launch_bounds__(256) void ln_kernel(const unsigned short* __restrict__ in,
                                                 const float* __restrict__ g,
                                                 const float* __restrict__ beta,
                                                 unsigned short* __restrict__ out) {
  const int row = blockIdx.x;
  const int t   = threadIdx.x;
  const u16x4 hv = *reinterpret_cast<const u16x4*>(in + (size_t)row * DIM + t * 4);
  const float v0 = bf2f(hv[0]), v1 = bf2f(hv[1]), v2 = bf2f(hv[2]), v3 = bf2f(hv[3]);
  float sum = v0 + v1 + v2 + v3;
  float sq  = v0 * v0 + v1 * v1 + v2 * v2 + v3 * v3;
  for (int off = 32; off; off >>= 1) {
    sum += __shfl_xor(sum, off);
    sq  += __shfl_xor(sq, off);
  }
  __shared__ float red[8];
  if ((t & 63) == 0) { red[t >> 6] = sum; red[4 + (t >> 6)] = sq; }
  __syncthreads();
  sum = red[0] + red[1] + red[2] + red[3];
  sq  = red[4] + red[5] + red[6] + red[7];
  const float mu  = sum * (1.f / DIM);
  const float var = sq * (1.f / DIM) - mu * mu;
  const float rs  = 1.f / sqrtf(var + 1e-5f);
  const float4 gv = *reinterpret_cast<const float4*>(g + t * 4);
  const float4 bv = *reinterpret_cast<const float4*>(beta + t * 4);
  u16x4 o;
  o[0] = f2bf((v0 - mu) * rs * gv.x + bv.x);
  o[1] = f2bf((v1 - mu) * rs * gv.y + bv.y);
  o[2] = f2bf((v2 - mu) * rs * gv.z + bv.z);
  o[3] = f2bf((v3 - mu) * rs * gv.w + bv.w);
  *reinterpret_cast<u16x4*>(out + (size_t)row * DIM + t * 4) = o;
}

// ---------------------------------------------------------------- launch
extern "C" void kernel_launch(void* const* d_in, const int* in_sizes, int n_in,
                              void* d_out, int out_size, void* d_ws, size_t ws_size,
                              hipStream_t stream) {
  const float* x    = (const float*)d_in[0];
  const float* xt   = (const float*)d_in[1];
  const float* Wq   = (const float*)d_in[2];
  const float* Wk   = (const float*)d_in[3];
  const float* Wv   = (const float*)d_in[4];
  const float* gate = (const float*)d_in[5];
  const float* lng  = (const float*)d_in[6];
  const float* lnbt = (const float*)d_in[7];
  const float* Wp   = (const float*)d_in[8];
  const float* bp   = (const float*)d_in[9];

  char* ws = (char*)d_ws;
  unsigned short* xkvb = (unsigned short*)(ws + 0);          // 18,087,936
  unsigned short* Wqkv = (unsigned short*)(ws + 18087936);   //  6,291,456
  unsigned short* Qb   = (unsigned short*)(ws + 24379392);   // 16,777,216
  unsigned short* Kb   = (unsigned short*)(ws + 41156608);   // 18,087,936
  unsigned short* Vtb  = (unsigned short*)(ws + 59244544);   // 18,087,936 (end 77,332,480)
  unsigned short* attnb = xkvb;   // xkv dead after QKV GEMM
  unsigned short* lnob  = Qb;     // Q dead after attention
  unsigned short* Wpb   = Wqkv;   // Wqkv dead after QKV GEMM

  cast_x_kernel<<<dim3((NB * NSEQ * DIM / 4 + 255) / 256), 256, 0, stream>>>(x, xkvb);
  cast_xt_kernel<<<dim3((NB * NP * DIM / 4 + 255) / 256), 256, 0, stream>>>(xt, xkvb);
  zero_hole_kernel<<<dim3((NB * 3 * DIM / 4 + 255) / 256), 256, 0, stream>>>(xkvb);
  const int w4 = DIM * DIM / 4;
  cast_kernel<<<dim3((w4 + 255) / 256), 256, 0, stream>>>(Wq, Wqkv, w4, QSCALE);
  cast_kernel<<<dim3((w4 + 255) / 256), 256, 0, stream>>>(Wk, Wqkv + DIM * DIM, w4, 1.0f);
  cast_kernel<<<dim3((w4 + 255) / 256), 256, 0, stream>>>(Wv, Wqkv + 2 * DIM * DIM, w4, 1.0f);

  gemm_qkv<<<dim3(69 * 24), 256, 0, stream>>>(xkvb, Wqkv, Qb, Kb, Vtb);

  attn_mfma<<<dim3(128, 8), 256, 0, stream>>>(Qb, Kb, Vtb, gate, attnb);

  cast_kernel<<<dim3((w4 + 255) / 256), 256, 0, stream>>>(Wp, Wpb, w4, 1.0f);
  ln_kernel<<<dim3(NB * NSEQ), 256, 0, stream>>>(attnb, lng, lnbt, lnob);
  gemm_out<<<dim3(64, 8), 256, 0, stream>>>(lnob, Wpb, (float*)d_out, bp);
}

// Round 15
// 249.367 us; speedup vs baseline: 1.0888x; 1.0295x over previous
//
#include <hip/hip_runtime.h>
#include <stdint.h>

#define DIM   1024
#define NB    8
#define NSEQ  1024
#define NP    77
#define NH    16
#define NKVR  1104     // padded key space: text 0..76, hole 77..79, x 80..1103
#define KVP   1104     // Vt row length (kv), multiple of 8
#define NTILE 18       // ceil(1152/64) key tiles of 64
#define PLD   68       // P LDS row stride (f32): multiple of 4 -> b128 reads stay aligned
#define QSCALE 0.18033688011112042f   // 0.125 * log2(e): folded into Wq at cast

typedef short          bf16x8 __attribute__((ext_vector_type(8)));
typedef float          f32x4  __attribute__((ext_vector_type(4)));
typedef unsigned short u16x8  __attribute__((ext_vector_type(8)));
typedef unsigned short u16x4  __attribute__((ext_vector_type(4)));
typedef unsigned int   u32x4  __attribute__((ext_vector_type(4)));

__device__ __forceinline__ float bf2f(unsigned short h) {
  return __uint_as_float(((unsigned int)h) << 16);
}
__device__ __forceinline__ unsigned short f2bf(float f) {
  unsigned int u = __float_as_uint(f);
  unsigned int r = u + 0x7FFFu + ((u >> 16) & 1u);   // RNE
  return (unsigned short)(r >> 16);
}
// pack two f32 -> 2x bf16 (RNE), lo -> bits[15:0]
__device__ __forceinline__ unsigned int cvt_pk_bf16(float lo, float hi) {
  unsigned int r;
  asm volatile("v_cvt_pk_bf16_f32 %0, %1, %2" : "=v"(r) : "v"(lo), "v"(hi));
  return r;
}

// ---------------------------------------------------------------- casts
__global__ __launch_bounds__(256) void cast_kernel(const float* __restrict__ in,
                                                   unsigned short* __restrict__ out,
                                                   int n4, float scale) {
  int i = blockIdx.x * 256 + threadIdx.x;
  if (i >= n4) return;
  float4 v = reinterpret_cast<const float4*>(in)[i];
  u16x4 o;
  o[0] = f2bf(v.x * scale); o[1] = f2bf(v.y * scale);
  o[2] = f2bf(v.z * scale); o[3] = f2bf(v.w * scale);
  reinterpret_cast<u16x4*>(out)[i] = o;
}

// x [8,1024,1024] f32 -> xkv rows batch*1104 + 80 + r
__global__ __launch_bounds__(256) void cast_x_kernel(const float* __restrict__ in,
                                                     unsigned short* __restrict__ xkv) {
  int i = blockIdx.x * 256 + threadIdx.x;
  if (i >= (NB * NSEQ * DIM) / 4) return;
  const int e    = i * 4;
  const int row  = e >> 10;
  const int cin  = e & 1023;
  const int batch = row >> 10;
  const int r     = row & 1023;
  float4 v = *reinterpret_cast<const float4*>(in + (size_t)e);
  u16x4 o;
  o[0] = f2bf(v.x); o[1] = f2bf(v.y); o[2] = f2bf(v.z); o[3] = f2bf(v.w);
  *reinterpret_cast<u16x4*>(xkv + (size_t)(batch * NKVR + 80 + r) * DIM + cin) = o;
}

// x_text [8,77,1024] f32 -> xkv rows batch*1104 + r
__global__ __launch_bounds__(256) void cast_xt_kernel(const float* __restrict__ in,
                                                      unsigned short* __restrict__ xkv) {
  int i = blockIdx.x * 256 + threadIdx.x;
  if (i >= (NB * NP * DIM) / 4) return;
  const int e    = i * 4;
  const int row  = e >> 10;
  const int cin  = e & 1023;
  const int batch = row / NP;
  const int r     = row - batch * NP;
  float4 v = *reinterpret_cast<const float4*>(in + (size_t)e);
  u16x4 o;
  o[0] = f2bf(v.x); o[1] = f2bf(v.y); o[2] = f2bf(v.z); o[3] = f2bf(v.w);
  *reinterpret_cast<u16x4*>(xkv + (size_t)(batch * NKVR + r) * DIM + cin) = o;
}

// zero xkv hole rows (77..79 per batch)
__global__ __launch_bounds__(256) void zero_hole_kernel(unsigned short* __restrict__ xkv) {
  int i = blockIdx.x * 256 + threadIdx.x;
  if (i >= (NB * 3 * DIM) / 4) return;
  const int e    = i * 4;
  const int row  = e >> 10;
  const int cin  = e & 1023;
  const int batch = row / 3;
  const int hr    = row - batch * 3;
  u16x4 z = {0, 0, 0, 0};
  *reinterpret_cast<u16x4*>(xkv + (size_t)(batch * NKVR + 77 + hr) * DIM + cin) = z;
}

// ------------------------------------------------------- async global->LDS
__device__ __forceinline__ void gload_lds16(const void* g, void* l) {
  __builtin_amdgcn_global_load_lds(
      (const __attribute__((address_space(1))) void*)g,
      (__attribute__((address_space(3))) void*)l, 16, 0, 0);
}

// ---------------------------------------------------------------- fused QKV GEMM
// A = xkv [8832][1024], B = Wqkv [3072][1024] (rows: Wq*QSCALE, Wk, Wv).
// grid: 1656 blocks (69 x 24), XCD-swizzled.
__global__ __launch_bounds__(256) void gemm_qkv(
    const unsigned short* __restrict__ A, const unsigned short* __restrict__ B,
    unsigned short* __restrict__ Qo, unsigned short* __restrict__ Ko,
    unsigned short* __restrict__ Vto) {
  __shared__ __align__(16) unsigned short As[128 * 32];
  __shared__ __align__(16) unsigned short Bs[128 * 32];
  const int id   = blockIdx.x;
  const int sid  = (id & 7) * 207 + (id >> 3);     // XCD swizzle (bijective)
  const int bx   = sid / 24;
  const int by   = sid - bx * 24;
  const int m0   = bx * 128;
  const int n0   = by * 128;
  const int t    = threadIdx.x;
  const int w    = t >> 6;
  const int lane = t & 63;
  const int wr   = w >> 1, wc = w & 1;
  const int lr   = lane & 15;
  const int k0   = (lane >> 4) * 8;

  f32x4 acc[4][4];
#pragma unroll
  for (int i = 0; i < 4; ++i)
#pragma unroll
    for (int j = 0; j < 4; ++j) acc[i][j] = f32x4{0.f, 0.f, 0.f, 0.f};

  for (int kt = 0; kt < 32; ++kt) {
#pragma unroll
    for (int p = 0; p < 2; ++p) {
      const int c   = p * 256 + t;
      const int row = c >> 2;
      const int cid = c & 3;
      gload_lds16(A + (size_t)(m0 + row) * DIM + kt * 32 + cid * 8,
                  (char*)As + p * 4096 + w * 1024);
      gload_lds16(B + (size_t)(n0 + row) * DIM + kt * 32 + cid * 8,
                  (char*)Bs + p * 4096 + w * 1024);
    }
    __syncthreads();
    bf16x8 af[4], bfr[4];
#pragma unroll
    for (int mi = 0; mi < 4; ++mi)
      af[mi] = *reinterpret_cast<const bf16x8*>(As + (wr * 64 + mi * 16 + lr) * 32 + k0);
#pragma unroll
    for (int ni = 0; ni < 4; ++ni)
      bfr[ni] = *reinterpret_cast<const bf16x8*>(Bs + (wc * 64 + ni * 16 + lr) * 32 + k0);
#pragma unroll
    for (int mi = 0; mi < 4; ++mi)
#pragma unroll
      for (int ni = 0; ni < 4; ++ni)
        acc[mi][ni] = __builtin_amdgcn_mfma_f32_16x16x32_bf16(af[mi], bfr[ni], acc[mi][ni], 0, 0, 0);
    __syncthreads();
  }

  const int rq  = lane >> 4;
  const int seg = n0 >> 10;          // 0=Q, 1=K, 2=V
  if (seg == 0) {
#pragma unroll
    for (int mi = 0; mi < 4; ++mi) {
#pragma unroll
      for (int i = 0; i < 4; ++i) {
        const int m     = m0 + wr * 64 + mi * 16 + rq * 4 + i;
        const int batch = m / NKVR;
        const int kv    = m - batch * NKVR;
        if (kv < 80) continue;                       // text/hole rows: no Q
        const size_t qrow = (size_t)batch * NSEQ + (kv - 80);
#pragma unroll
        for (int ni = 0; ni < 4; ++ni) {
          const int col = n0 + wc * 64 + ni * 16 + lr;
          Qo[qrow * DIM + col] = f2bf(acc[mi][ni][i]);
        }
      }
    }
  } else if (seg == 1) {
#pragma unroll
    for (int mi = 0; mi < 4; ++mi) {
#pragma unroll
      for (int i = 0; i < 4; ++i) {
        const int m = m0 + wr * 64 + mi * 16 + rq * 4 + i;
#pragma unroll
        for (int ni = 0; ni < 4; ++ni) {
          const int col = n0 + wc * 64 + ni * 16 + lr - 1024;
          Ko[(size_t)m * DIM + col] = f2bf(acc[mi][ni][i]);
        }
      }
    }
  } else {
#pragma unroll
    for (int mi = 0; mi < 4; ++mi) {
      const int mb    = m0 + wr * 64 + mi * 16 + rq * 4;
      const int batch = mb / NKVR;
      const int kv    = mb - batch * NKVR;           // 4-aligned, no batch crossing
#pragma unroll
      for (int ni = 0; ni < 4; ++ni) {
        const int col = n0 + wc * 64 + ni * 16 + lr - 2048;
        const int hh = col >> 6, dd = col & 63;
        u16x4 o;
        o[0] = f2bf(acc[mi][ni][0]); o[1] = f2bf(acc[mi][ni][1]);
        o[2] = f2bf(acc[mi][ni][2]); o[3] = f2bf(acc[mi][ni][3]);
        *reinterpret_cast<u16x4*>(Vto +
            ((size_t)((batch * NH + hh) * 64 + dd)) * KVP + kv) = o;
      }
    }
  }
}

// ---------------------------------------------------------------- out GEMM
__global__ __launch_bounds__(256) void gemm_out(
    const unsigned short* __restrict__ A, const unsigned short* __restrict__ B,
    float* __restrict__ C, const float* __restrict__ bias) {
  __shared__ __align__(16) unsigned short As[128 * 32];
  __shared__ __align__(16) unsigned short Bs[128 * 32];
  const int t    = threadIdx.x;
  const int w    = t >> 6;
  const int lane = t & 63;
  const int m0   = blockIdx.x * 128;
  const int n0   = blockIdx.y * 128;
  const int wr   = w >> 1, wc = w & 1;
  const int lr   = lane & 15;
  const int k0   = (lane >> 4) * 8;

  f32x4 acc[4][4];
#pragma unroll
  for (int i = 0; i < 4; ++i)
#pragma unroll
    for (int j = 0; j < 4; ++j) acc[i][j] = f32x4{0.f, 0.f, 0.f, 0.f};

  for (int kt = 0; kt < 32; ++kt) {
#pragma unroll
    for (int p = 0; p < 2; ++p) {
      const int c   = p * 256 + t;
      const int row = c >> 2;
      const int cid = c & 3;
      gload_lds16(A + (size_t)(m0 + row) * DIM + kt * 32 + cid * 8,
                  (char*)As + p * 4096 + w * 1024);
      gload_lds16(B + (size_t)(n0 + row) * DIM + kt * 32 + cid * 8,
                  (char*)Bs + p * 4096 + w * 1024);
    }
    __syncthreads();
    bf16x8 af[4], bfr[4];
#pragma unroll
    for (int mi = 0; mi < 4; ++mi)
      af[mi] = *reinterpret_cast<const bf16x8*>(As + (wr * 64 + mi * 16 + lr) * 32 + k0);
#pragma unroll
    for (int ni = 0; ni < 4; ++ni)
      bfr[ni] = *reinterpret_cast<const bf16x8*>(Bs + (wc * 64 + ni * 16 + lr) * 32 + k0);
#pragma unroll
    for (int mi = 0; mi < 4; ++mi)
#pragma unroll
      for (int ni = 0; ni < 4; ++ni)
        acc[mi][ni] = __builtin_amdgcn_mfma_f32_16x16x32_bf16(af[mi], bfr[ni], acc[mi][ni], 0, 0, 0);
    __syncthreads();
  }

  const int rq = lane >> 4;
#pragma unroll
  for (int mi = 0; mi < 4; ++mi) {
#pragma unroll
    for (int i = 0; i < 4; ++i) {
      const int m = m0 + wr * 64 + mi * 16 + rq * 4 + i;
#pragma unroll
      for (int ni = 0; ni < 4; ++ni) {
        const int col = n0 + wc * 64 + ni * 16 + lr;
        C[(size_t)m * DIM + col] = acc[mi][ni][i] + bias[col];
      }
    }
  }
}

// ---------------------------------------------------------------- MFMA attention
// R8 structure: grid (128 bh, 8 qtile), block 256 (4 waves x 32 q-rows).
// Single-buffered per-tile pipeline: K batch-load -> QK -> V issue-early
// -> mask/exp2/P-LDS -> PV from registers. Q pre-scaled by 0.125*log2e.
__global__ __launch_bounds__(256) void attn_mfma(
    const unsigned short* __restrict__ Q, const unsigned short* __restrict__ K,
    const unsigned short* __restrict__ Vt, const float* __restrict__ gate,
    unsigned short* __restrict__ O) {
  const int wid  = threadIdx.x >> 6;
  const int lane = threadIdx.x & 63;
  const int lr   = lane & 15;
  const int lg   = lane >> 4;
  const int bh   = blockIdx.x;
  const int b    = bh >> 4;
  const int h    = bh & 15;
  const int q0   = blockIdx.y * 128 + wid * 32;

  __shared__ __align__(16) float p_lds[4][32 * PLD];   // per-wave f32 P tile

  bf16x8 aq[2][2];
#pragma unroll
  for (int mi = 0; mi < 2; ++mi)
#pragma unroll
    for (int kf = 0; kf < 2; ++kf)
      aq[mi][kf] = *reinterpret_cast<const bf16x8*>(
          Q + ((size_t)(b * NSEQ + q0 + mi * 16 + lr)) * DIM + h * 64 + kf * 32 + lg * 8);

  f32x4 accO[2][4];
#pragma unroll
  for (int mi = 0; mi < 2; ++mi)
#pragma unroll
    for (int n = 0; n < 4; ++n) accO[mi][n] = f32x4{0.f, 0.f, 0.f, 0.f};
  float lsum[2][4];
#pragma unroll
  for (int mi = 0; mi < 2; ++mi)
#pragma unroll
    for (int r = 0; r < 4; ++r) lsum[mi][r] = 0.f;

  const unsigned short* Kbase  = K  + ((size_t)b * NKVR) * DIM + h * 64 + lg * 8;
  const unsigned short* Vtbase = Vt + ((size_t)((b * NH + h) * 64)) * KVP;
  float* pl = p_lds[wid];

  for (int tkv = 0; tkv < NTILE; ++tkv) {
    const int kv0 = tkv * 64;
    // ---- issue all K loads for this tile (batched; consumed by QK below)
    bf16x8 bk[4][2];
#pragma unroll
    for (int ni = 0; ni < 4; ++ni) {
      int kvn = kv0 + ni * 16 + lr;
      kvn = kvn < (NKVR - 1) ? kvn : (NKVR - 1);
      const unsigned short* kr = Kbase + (size_t)kvn * DIM;
#pragma unroll
      for (int kf = 0; kf < 2; ++kf)
        bk[ni][kf] = *reinterpret_cast<const bf16x8*>(kr + kf * 32);
    }
    // ---- S = Q K^T  (Q pre-scaled; S in log2 units)
    f32x4 S[2][4];
#pragma unroll
    for (int mi = 0; mi < 2; ++mi)
#pragma unroll
      for (int ni = 0; ni < 4; ++ni) S[mi][ni] = f32x4{0.f, 0.f, 0.f, 0.f};
#pragma unroll
    for (int ni = 0; ni < 4; ++ni)
#pragma unroll
      for (int kf = 0; kf < 2; ++kf)
#pragma unroll
        for (int mi = 0; mi < 2; ++mi)
          S[mi][ni] = __builtin_amdgcn_mfma_f32_16x16x32_bf16(aq[mi][kf], bk[ni][kf], S[mi][ni], 0, 0, 0);
    // ---- issue all V loads now; they fly during exp2 + P-LDS roundtrip
    bf16x8 bv[4][2];
#pragma unroll
    for (int n = 0; n < 4; ++n) {
      const unsigned short* vr = Vtbase + (size_t)(n * 16 + lr) * KVP;
#pragma unroll
      for (int kf = 0; kf < 2; ++kf) {
        int kvb = kv0 + kf * 32 + lg * 8;
        kvb = kvb < (KVP - 8) ? kvb : (KVP - 8);
        bv[n][kf] = *reinterpret_cast<const bf16x8*>(vr + kvb);
      }
    }
    // ---- mask (tiles containing key 0, the hole 77..79, or tail >=1104)
    if (tkv < 2 || tkv == NTILE - 1) {
#pragma unroll
      for (int ni = 0; ni < 4; ++ni) {
        const int gk = kv0 + ni * 16 + lr;
        const bool bad = (gk == 0) || ((unsigned)(gk - 77) < 3u) || (gk >= NKVR);
        if (bad) {
#pragma unroll
          for (int mi = 0; mi < 2; ++mi)
#pragma unroll
            for (int r = 0; r < 4; ++r) S[mi][ni][r] = -1.0e30f;
        }
      }
    }
    // ---- exp2, per-lane partial sums, P -> LDS (f32)
#pragma unroll
    for (int mi = 0; mi < 2; ++mi) {
#pragma unroll
      for (int ni = 0; ni < 4; ++ni) {
#pragma unroll
        for (int r = 0; r < 4; ++r)
          S[mi][ni][r] = __builtin_exp2f(S[mi][ni][r]);
      }
#pragma unroll
      for (int r = 0; r < 4; ++r)
        lsum[mi][r] += (S[mi][0][r] + S[mi][1][r]) + (S[mi][2][r] + S[mi][3][r]);
#pragma unroll
      for (int ni = 0; ni < 4; ++ni) {
        float* pw = pl + (size_t)(mi * 16 + lg * 4) * PLD + ni * 16 + lr;
        pw[0 * PLD] = S[mi][ni][0];
        pw[1 * PLD] = S[mi][ni][1];
        pw[2 * PLD] = S[mi][ni][2];
        pw[3 * PLD] = S[mi][ni][3];
      }
    }
    // ---- O += P V
    bf16x8 pa[2][2];
#pragma unroll
    for (int mi = 0; mi < 2; ++mi) {
#pragma unroll
      for (int kf = 0; kf < 2; ++kf) {
        const float* pr = pl + (size_t)(mi * 16 + lr) * PLD + kf * 32 + lg * 8;
        const float4 pa0 = *reinterpret_cast<const float4*>(pr);
        const float4 pa1 = *reinterpret_cast<const float4*>(pr + 4);
        u32x4 pk;
        pk[0] = cvt_pk_bf16(pa0.x, pa0.y);
        pk[1] = cvt_pk_bf16(pa0.z, pa0.w);
        pk[2] = cvt_pk_bf16(pa1.x, pa1.y);
        pk[3] = cvt_pk_bf16(pa1.z, pa1.w);
        pa[mi][kf] = __builtin_bit_cast(bf16x8, pk);
      }
    }
#pragma unroll
    for (int n = 0; n < 4; ++n)
#pragma unroll
      for (int kf = 0; kf < 2; ++kf)
#pragma unroll
        for (int mi = 0; mi < 2; ++mi)
          accO[mi][n] = __builtin_amdgcn_mfma_f32_16x16x32_bf16(pa[mi][kf], bv[n][kf], accO[mi][n], 0, 0, 0);
  }

  // ---- single cross-lane sum reduce, then epilogue
#pragma unroll
  for (int mi = 0; mi < 2; ++mi) {
#pragma unroll
    for (int r = 0; r < 4; ++r) {
      float s = lsum[mi][r];
      s += __shfl_xor(s, 1);
      s += __shfl_xor(s, 2);
      s += __shfl_xor(s, 4);
      s += __shfl_xor(s, 8);
      lsum[mi][r] = 1.f / s;
    }
  }
  const float gv = tanhf(gate[h]);
#pragma unroll
  for (int mi = 0; mi < 2; ++mi) {
#pragma unroll
    for (int n = 0; n < 4; ++n) {
      const float v0 = bf2f(Vtbase[(size_t)(n * 16 + lr) * KVP]);   // key 0
#pragma unroll
      for (int r = 0; r < 4; ++r) {
        const float o = accO[mi][n][r] * lsum[mi][r] + gv * v0;
        const int q = q0 + mi * 16 + lg * 4 + r;
        O[((size_t)(b * NSEQ + q)) * DIM + h * 64 + n * 16 + lr] = f2bf(o);
      }
    }
  }
}

// ---------------------------------------------------------------- LayerNorm
__global__ __launch_bounds__(256) void ln_kernel(const unsigned short* __restrict__ in,
                                                 const float* __restrict__ g,
                                                 const float* __restrict__ beta,
                                                 unsigned short* __restrict__ out) {
  const int row = blockIdx.x;
  const int t   = threadIdx.x;
  const u16x4 hv = *reinterpret_cast<const u16x4*>(in + (size_t)row * DIM + t * 4);
  const float v0 = bf2f(hv[0]), v1 = bf2f(hv[1]), v2 = bf2f(hv[2]), v3 = bf2f(hv[3]);
  float sum = v0 + v1 + v2 + v3;
  float sq  = v0 * v0 + v1 * v1 + v2 * v2 + v3 * v3;
  for (int off = 32; off; off >>= 1) {
    sum += __shfl_xor(sum, off);
    sq  += __shfl_xor(sq, off);
  }
  __shared__ float red[8];
  if ((t & 63) == 0) { red[t >> 6] = sum; red[4 + (t >> 6)] = sq; }
  __syncthreads();
  sum = red[0] + red[1] + red[2] + red[3];
  sq  = red[4] + red[5] + red[6] + red[7];
  const float mu  = sum * (1.f / DIM);
  const float var = sq * (1.f / DIM) - mu * mu;
  const float rs  = 1.f / sqrtf(var + 1e-5f);
  const float4 gv = *reinterpret_cast<const float4*>(g + t * 4);
  const float4 bv = *reinterpret_cast<const float4*>(beta + t * 4);
  u16x4 o;
  o[0] = f2bf((v0 - mu) * rs * gv.x + bv.x);
  o[1] = f2bf((v1 - mu) * rs * gv.y + bv.y);
  o[2] = f2bf((v2 - mu) * rs * gv.z + bv.z);
  o[3] = f2bf((v3 - mu) * rs * gv.w + bv.w);
  *reinterpret_cast<u16x4*>(out + (size_t)row * DIM + t * 4) = o;
}

// ---------------------------------------------------------------- launch
extern "C" void kernel_launch(void* const* d_in, const int* in_sizes, int n_in,
                              void* d_out, int out_size, void* d_ws, size_t ws_size,
                              hipStream_t stream) {
  const float* x    = (const float*)d_in[0];
  const float* xt   = (const float*)d_in[1];
  const float* Wq   = (const float*)d_in[2];
  const float* Wk   = (const float*)d_in[3];
  const float* Wv   = (const float*)d_in[4];
  const float* gate = (const float*)d_in[5];
  const float* lng  = (const float*)d_in[6];
  const float* lnbt = (const float*)d_in[7];
  const float* Wp   = (const float*)d_in[8];
  const float* bp   = (const float*)d_in[9];

  char* ws = (char*)d_ws;
  unsigned short* xkvb = (unsigned short*)(ws + 0);          // 18,087,936
  unsigned short* Wqkv = (unsigned short*)(ws + 18087936);   //  6,291,456
  unsigned short* Qb   = (unsigned short*)(ws + 24379392);   // 16,777,216
  unsigned short* Kb   = (unsigned short*)(ws + 41156608);   // 18,087,936
  unsigned short* Vtb  = (unsigned short*)(ws + 59244544);   // 18,087,936 (end 77,332,480)
  unsigned short* attnb = xkvb;   // xkv dead after QKV GEMM
  unsigned short* lnob  = Qb;     // Q dead after attention
  unsigned short* Wpb   = Wqkv;   // Wqkv dead after QKV GEMM

  cast_x_kernel<<<dim3((NB * NSEQ * DIM / 4 + 255) / 256), 256, 0, stream>>>(x, xkvb);
  cast_xt_kernel<<<dim3((NB * NP * DIM / 4 + 255) / 256), 256, 0, stream>>>(xt, xkvb);
  zero_hole_kernel<<<dim3((NB * 3 * DIM / 4 + 255) / 256), 256, 0, stream>>>(xkvb);
  const int w4 = DIM * DIM / 4;
  cast_kernel<<<dim3((w4 + 255) / 256), 256, 0, stream>>>(Wq, Wqkv, w4, QSCALE);
  cast_kernel<<<dim3((w4 + 255) / 256), 256, 0, stream>>>(Wk, Wqkv + DIM * DIM, w4, 1.0f);
  cast_kernel<<<dim3((w4 + 255) / 256), 256, 0, stream>>>(Wv, Wqkv + 2 * DIM * DIM, w4, 1.0f);

  gemm_qkv<<<dim3(69 * 24), 256, 0, stream>>>(xkvb, Wqkv, Qb, Kb, Vtb);

  attn_mfma<<<dim3(128, 8), 256, 0, stream>>>(Qb, Kb, Vtb, gate, attnb);

  cast_kernel<<<dim3((w4 + 255) / 256), 256, 0, stream>>>(Wp, Wpb, w4, 1.0f);
  ln_kernel<<<dim3(NB * NSEQ), 256, 0, stream>>>(attnb, lng, lnbt, lnob);
  gemm_out<<<dim3(64, 8), 256, 0, stream>>>(lnob, Wpb, (float*)d_out, bp);
}